// Round 3
// baseline (382.118 us; speedup 1.0000x reference)
//
#include <hip/hip_runtime.h>
#include <stdint.h>

#define HID   1024
#define NHEAD 16
#define HDIM  64
#define NV    2048
#define NA    16
#define NTOK  2064
#define BSZ   2
#define MROWS 4128   // 4096 video rows + 32 action rows
#define WSZ   1048576
// p = exp2(s * SCALE * log2(e) - 16)   [fixed-max softmax, exact after divide]
#define EXP_C1 0.18033688011112042f
#define EXP_C2 16.0f

typedef __bf16 bf16x8 __attribute__((ext_vector_type(8)));
typedef unsigned short u16x8 __attribute__((ext_vector_type(8)));
typedef unsigned short u16x4 __attribute__((ext_vector_type(4)));
typedef float f32x4 __attribute__((ext_vector_type(4)));

__device__ __forceinline__ unsigned short f2bf(float f) {  // RNE
  unsigned u = __builtin_bit_cast(unsigned, f);
  u += 0x7FFFu + ((u >> 16) & 1u);
  return (unsigned short)(u >> 16);
}
__device__ __forceinline__ unsigned short f2bf_trunc(float f) {
  return (unsigned short)(__builtin_bit_cast(unsigned, f) >> 16);
}
__device__ __forceinline__ void async_copy16(const void* g, void* l) {
  __builtin_amdgcn_global_load_lds(
      (const __attribute__((address_space(1))) unsigned int*)g,
      (__attribute__((address_space(3))) unsigned int*)l, 16, 0, 0);
}

// ---------------------------------------------------------------------------
// Kernel 0: fp32 -> bf16 convert. Wb = [Wq,Wk,Wv,Wqa,Wka,Wva,Wp,Wpa] (8 x 1M),
// Xb = video (rows 0..4095) || action (rows 4096..4127), row-major 1024.
// grid (512, 13), block 256, 8 elems/thread.
// ---------------------------------------------------------------------------
__global__ __launch_bounds__(256) void cvt_kernel(
    const float* __restrict__ W0, const float* __restrict__ W1,
    const float* __restrict__ W2, const float* __restrict__ W3,
    const float* __restrict__ W4, const float* __restrict__ W5,
    const float* __restrict__ W6, const float* __restrict__ W7,
    const float* __restrict__ video, const float* __restrict__ action,
    unsigned short* __restrict__ Wb, unsigned short* __restrict__ Xb)
{
  const int y = blockIdx.y;
  const size_t idx = ((size_t)blockIdx.x * 256 + threadIdx.x) * 8;
  const float* src; unsigned short* dst;
  if      (y == 0)  { src = W0; dst = Wb; }
  else if (y == 1)  { src = W1; dst = Wb + 1 * WSZ; }
  else if (y == 2)  { src = W2; dst = Wb + 2 * WSZ; }
  else if (y == 3)  { src = W3; dst = Wb + 3 * WSZ; }
  else if (y == 4)  { src = W4; dst = Wb + 4 * WSZ; }
  else if (y == 5)  { src = W5; dst = Wb + 5 * WSZ; }
  else if (y == 6)  { src = W6; dst = Wb + 6 * WSZ; }
  else if (y == 7)  { src = W7; dst = Wb + 7 * WSZ; }
  else if (y < 12)  { src = video + (size_t)(y - 8) * WSZ; dst = Xb + (size_t)(y - 8) * WSZ; }
  else              { if (idx >= (size_t)BSZ * NA * HID) return;
                      src = action; dst = Xb + (size_t)4096 * HID; }
  float4 f0 = *(const float4*)(src + idx);
  float4 f1 = *(const float4*)(src + idx + 4);
  u16x8 v;
  v[0]=f2bf(f0.x); v[1]=f2bf(f0.y); v[2]=f2bf(f0.z); v[3]=f2bf(f0.w);
  v[4]=f2bf(f1.x); v[5]=f2bf(f1.y); v[6]=f2bf(f1.z); v[7]=f2bf(f1.w);
  *(u16x8*)(dst + idx) = v;
}

// row -> (batch, token) in the joint (B,H,NTOK,D) space
__device__ __forceinline__ void row2bt(int rg, int& b, int& tok, bool& valid) {
  if (rg < 4096) { b = rg >> 11; tok = rg & 2047; valid = true; }
  else { int t = rg - 4096; b = t >> 4; tok = 2048 + (t & 15); valid = rg < MROWS; }
}

// ---------------------------------------------------------------------------
// Kernel 1: QKV GEMM, 128x128 tile, BK=32, global_load_lds staging.
// grid (8 n-tiles, 33 m-tiles, 3 z); block 256 (4 waves, each 64x64).
// m-tile 32 = action rows (uses action weights/bias). Epilogue: bias + RoPE
// (Q/K, video tokens) -> (B,H,NTOK,D); V -> transposed (B,H,D,NTOK).
// ---------------------------------------------------------------------------
__global__ __launch_bounds__(256) void qkv128_kernel(
    const unsigned short* __restrict__ Xb, const unsigned short* __restrict__ Wb,
    const float* __restrict__ bq, const float* __restrict__ bk,
    const float* __restrict__ bv, const float* __restrict__ bqa,
    const float* __restrict__ bka, const float* __restrict__ bva,
    unsigned short* __restrict__ Qo, unsigned short* __restrict__ Ko,
    unsigned short* __restrict__ Vt)
{
  __shared__ unsigned short As[128 * 32];
  __shared__ unsigned short Bs[128 * 32];

  const int tid  = threadIdx.x;
  const int w    = tid >> 6;
  const int l    = tid & 63;
  const int quad = l >> 4;
  const int l16  = l & 15;
  const int lrow = l >> 2;
  const int lk   = (l & 3) * 8;
  const int z    = blockIdx.z;
  const int m0   = blockIdx.y * 128;
  const int n0   = blockIdx.x * 128;
  const bool atile = (blockIdx.y == 32);

  const unsigned short* Wm = Wb + (size_t)(atile ? 3 + z : z) * WSZ;
  const float* bias = (z == 0) ? (atile ? bqa : bq)
                    : (z == 1) ? (atile ? bka : bk)
                               : (atile ? bva : bv);

  const int am = (w & 1) * 64;
  const int bn = (w >> 1) * 64;

  f32x4 acc[4][4] = {};

  for (int kt = 0; kt < HID; kt += 32) {
    __syncthreads();
#pragma unroll
    for (int i = 0; i < 2; i++) {
      int trow = w * 32 + i * 16;
      int arow = min(m0 + trow + lrow, MROWS - 1);
      async_copy16(Xb + (size_t)arow * HID + kt + lk, &As[trow * 32]);
      async_copy16(Wm + (size_t)(n0 + trow + lrow) * HID + kt + lk, &Bs[trow * 32]);
    }
    __syncthreads();

    bf16x8 af[4], bf[4];
#pragma unroll
    for (int mi = 0; mi < 4; mi++)
      af[mi] = __builtin_bit_cast(bf16x8, *(const u16x8*)&As[(am + mi * 16 + l16) * 32 + quad * 8]);
#pragma unroll
    for (int ni = 0; ni < 4; ni++)
      bf[ni] = __builtin_bit_cast(bf16x8, *(const u16x8*)&Bs[(bn + ni * 16 + l16) * 32 + quad * 8]);
#pragma unroll
    for (int mi = 0; mi < 4; mi++)
#pragma unroll
      for (int ni = 0; ni < 4; ni++)
        acc[mi][ni] = __builtin_amdgcn_mfma_f32_16x16x32_bf16(af[mi], bf[ni], acc[mi][ni], 0, 0, 0);
  }

  if (z < 2) {
    unsigned short* O = (z == 0) ? Qo : Ko;
#pragma unroll
    for (int mi = 0; mi < 4; mi++) {
      const int rgb = m0 + am + mi * 16 + quad * 4;
#pragma unroll
      for (int ni = 0; ni < 4; ni++) {
        const int gcol = n0 + bn + ni * 16 + l16;
        const int head = gcol >> 6, col = gcol & 63;
        const float bias_v = bias[gcol];
        const int seg = (col >= 40) ? 2 : (col >= 20) ? 1 : 0;
        const int tin = col - seg * 20;
        const float om = exp2f(-(float)(tin >> 1) * 1.3287712379549449f);
        const bool evn = !(tin & 1);
#pragma unroll
        for (int r = 0; r < 4; r++) {
          int rg = rgb + r;
          int b, tok; bool valid;
          row2bt(rg, b, tok, valid);
          float val = acc[mi][ni][r] + bias_v;
          float part = __shfl_xor(val, 1);
          if (tok < 2048 && col < 60) {
            int dp = tok >> 8, hp = (tok >> 4) & 15, wp = tok & 15;
            float pos = (seg == 0) ? (float)dp : (seg == 1) ? (float)hp : (float)wp;
            float fr = pos * om;
            float cs = cosf(fr), sn = sinf(fr);
            val = evn ? (val * cs - part * sn) : (val * cs + part * sn);
          }
          if (valid)
            O[(((size_t)b * NHEAD + head) * NTOK + tok) * HDIM + col] = f2bf(val);
        }
      }
    }
  } else {
#pragma unroll
    for (int mi = 0; mi < 4; mi++) {
      const int rgb = m0 + am + mi * 16 + quad * 4;
      int b, tok; bool valid;
      row2bt(rgb, b, tok, valid);
#pragma unroll
      for (int ni = 0; ni < 4; ni++) {
        const int gcol = n0 + bn + ni * 16 + l16;
        const int head = gcol >> 6, d = gcol & 63;
        const float bias_v = bias[gcol];
        u16x4 pk;
#pragma unroll
        for (int r = 0; r < 4; r++) pk[r] = f2bf(acc[mi][ni][r] + bias_v);
        if (valid)
          *(u16x4*)&Vt[(((size_t)b * NHEAD + head) * HDIM + d) * NTOK + tok] = pk;
      }
    }
  }
}

// ---------------------------------------------------------------------------
// Kernel 2: flash attention, fixed-max softmax. grid (33 q-tiles, B*H).
// ctx rows: video b*2048+tok, action 4096+b*16+(tok-2048)  [bf16, stride HID]
// ---------------------------------------------------------------------------
__global__ __launch_bounds__(256) void attn_kernel(
    const unsigned short* __restrict__ Q,
    const unsigned short* __restrict__ K,
    const unsigned short* __restrict__ Vt,
    unsigned short* __restrict__ ctx)
{
  __shared__ unsigned short Qs[64][72];
  __shared__ unsigned short Ks[64][72];
  __shared__ unsigned short Vts[64][72];
  __shared__ unsigned short Ps[4][16][68];

  const int tid  = threadIdx.x;
  const int wave = tid >> 6;
  const int lane = tid & 63;
  const int quad = lane >> 4;
  const int l16  = lane & 15;
  const int bh   = blockIdx.y;
  const int q0   = blockIdx.x * 64;
  const unsigned short* Qp  = Q  + (size_t)bh * NTOK * HDIM;
  const unsigned short* Kp  = K  + (size_t)bh * NTOK * HDIM;
  const unsigned short* Vtp = Vt + (size_t)bh * HDIM * NTOK;

  const int r  = tid >> 2;
  const int c0 = (tid & 3) * 8;

  {
    int row = min(q0 + r, NTOK - 1);
#pragma unroll
    for (int cc = 0; cc < 2; cc++) {
      int c = c0 + cc * 32;
      *(u16x8*)&Qs[r][c] = *(const u16x8*)(Qp + (size_t)row * HDIM + c);
    }
  }

  u16x8 ones_u;
#pragma unroll
  for (int i = 0; i < 8; i++) ones_u[i] = 0x3F80;
  const bf16x8 ones = __builtin_bit_cast(bf16x8, ones_u);

  f32x4 oacc[4] = {};
  f32x4 lacc = {};

  for (int kv0 = 0; kv0 < NTOK; kv0 += 64) {
    __syncthreads();
    {
      int row = min(kv0 + r, NTOK - 1);
#pragma unroll
      for (int cc = 0; cc < 2; cc++) {
        int c = c0 + cc * 32;
        *(u16x8*)&Ks[r][c]  = *(const u16x8*)(Kp + (size_t)row * HDIM + c);
        *(u16x8*)&Vts[r][c] = *(const u16x8*)(Vtp + (size_t)r * NTOK + kv0 + c);
      }
    }
    __syncthreads();

    f32x4 sacc[4] = {};
#pragma unroll
    for (int kq = 0; kq < 64; kq += 32) {
      bf16x8 a = __builtin_bit_cast(bf16x8, *(const u16x8*)&Qs[wave * 16 + l16][kq + quad * 8]);
#pragma unroll
      for (int nt = 0; nt < 4; nt++) {
        bf16x8 bb = __builtin_bit_cast(bf16x8, *(const u16x8*)&Ks[nt * 16 + l16][kq + quad * 8]);
        sacc[nt] = __builtin_amdgcn_mfma_f32_16x16x32_bf16(a, bb, sacc[nt], 0, 0, 0);
      }
    }

#pragma unroll
    for (int nt = 0; nt < 4; nt++) {
      bool valid = (kv0 + nt * 16 + l16) < NTOK;
#pragma unroll
      for (int rr = 0; rr < 4; rr++) {
        float p = exp2f(__builtin_fmaf(sacc[nt][rr], EXP_C1, -EXP_C2));
        p = valid ? p : 0.f;
        Ps[wave][quad * 4 + rr][nt * 16 + l16] = f2bf_trunc(p);
      }
    }

#pragma unroll
    for (int kq = 0; kq < 64; kq += 32) {
      u16x4 alo = *(const u16x4*)&Ps[wave][l16][kq + quad * 8];
      u16x4 ahi = *(const u16x4*)&Ps[wave][l16][kq + quad * 8 + 4];
      bf16x8 a = __builtin_bit_cast(bf16x8,
          __builtin_shufflevector(alo, ahi, 0, 1, 2, 3, 4, 5, 6, 7));
#pragma unroll
      for (int nt = 0; nt < 4; nt++) {
        bf16x8 bb = __builtin_bit_cast(bf16x8, *(const u16x8*)&Vts[nt * 16 + l16][kq + quad * 8]);
        oacc[nt] = __builtin_amdgcn_mfma_f32_16x16x32_bf16(a, bb, oacc[nt], 0, 0, 0);
      }
      lacc = __builtin_amdgcn_mfma_f32_16x16x32_bf16(a, ones, lacc, 0, 0, 0);
    }
  }

  const int b = bh >> 4, h = bh & 15;
  float rl[4];
#pragma unroll
  for (int rr = 0; rr < 4; rr++) rl[rr] = 1.f / lacc[rr];
#pragma unroll
  for (int nt = 0; nt < 4; nt++) {
#pragma unroll
    for (int rr = 0; rr < 4; rr++) {
      int token = q0 + wave * 16 + quad * 4 + rr;
      if (token < NTOK) {
        int row = (token < 2048) ? (b * 2048 + token) : (4096 + b * NA + (token - 2048));
        int d = nt * 16 + l16;
        ctx[(size_t)row * HID + h * HDIM + d] = f2bf(oacc[nt][rr] * rl[rr]);
      }
    }
  }
}

// ---------------------------------------------------------------------------
// Kernel 3: output projection, 128x128 tile GEMM. grid (8 n-tiles, 33 m-tiles).
// m-tile 32 = action rows -> Wpa/bpa. Writes fp32 d_out (row-linear).
// ---------------------------------------------------------------------------
__global__ __launch_bounds__(256) void proj128_kernel(
    const unsigned short* __restrict__ ctx, const unsigned short* __restrict__ Wb,
    const float* __restrict__ bp, const float* __restrict__ bpa,
    float* __restrict__ out)
{
  __shared__ unsigned short As[128 * 32];
  __shared__ unsigned short Bs[128 * 32];

  const int tid  = threadIdx.x;
  const int w    = tid >> 6;
  const int l    = tid & 63;
  const int quad = l >> 4;
  const int l16  = l & 15;
  const int lrow = l >> 2;
  const int lk   = (l & 3) * 8;
  const int m0   = blockIdx.y * 128;
  const int n0   = blockIdx.x * 128;
  const bool atile = (blockIdx.y == 32);

  const unsigned short* Wm = Wb + (size_t)(atile ? 7 : 6) * WSZ;
  const float* bias = atile ? bpa : bp;

  const int am = (w & 1) * 64;
  const int bn = (w >> 1) * 64;

  f32x4 acc[4][4] = {};

  for (int kt = 0; kt < HID; kt += 32) {
    __syncthreads();
#pragma unroll
    for (int i = 0; i < 2; i++) {
      int trow = w * 32 + i * 16;
      int arow = min(m0 + trow + lrow, MROWS - 1);
      async_copy16(ctx + (size_t)arow * HID + kt + lk, &As[trow * 32]);
      async_copy16(Wm + (size_t)(n0 + trow + lrow) * HID + kt + lk, &Bs[trow * 32]);
    }
    __syncthreads();

    bf16x8 af[4], bf[4];
#pragma unroll
    for (int mi = 0; mi < 4; mi++)
      af[mi] = __builtin_bit_cast(bf16x8, *(const u16x8*)&As[(am + mi * 16 + l16) * 32 + quad * 8]);
#pragma unroll
    for (int ni = 0; ni < 4; ni++)
      bf[ni] = __builtin_bit_cast(bf16x8, *(const u16x8*)&Bs[(bn + ni * 16 + l16) * 32 + quad * 8]);
#pragma unroll
    for (int mi = 0; mi < 4; mi++)
#pragma unroll
      for (int ni = 0; ni < 4; ni++)
        acc[mi][ni] = __builtin_amdgcn_mfma_f32_16x16x32_bf16(af[mi], bf[ni], acc[mi][ni], 0, 0, 0);
  }

#pragma unroll
  for (int mi = 0; mi < 4; mi++) {
    const int rgb = m0 + am + mi * 16 + quad * 4;
#pragma unroll
    for (int ni = 0; ni < 4; ni++) {
      const int gcol = n0 + bn + ni * 16 + l16;
      const float bias_v = bias[gcol];
#pragma unroll
      for (int r = 0; r < 4; r++) {
        int rg = rgb + r;
        if (rg < MROWS) out[(size_t)rg * HID + gcol] = acc[mi][ni][r] + bias_v;
      }
    }
  }
}

// ---------------------------------------------------------------------------
extern "C" void kernel_launch(void* const* d_in, const int* in_sizes, int n_in,
                              void* d_out, int out_size, void* d_ws, size_t ws_size,
                              hipStream_t stream) {
  const float* A[18];
  if (in_sizes[0] == HID * HID) {
    for (int i = 0; i < 18; i++) A[i] = (const float*)d_in[i];
  } else {
    A[16] = (const float*)d_in[0];
    A[17] = (const float*)d_in[1];
    for (int i = 0; i < 16; i++) A[i] = (const float*)d_in[i + 2];
  }
  const float *Wq = A[0], *bq = A[1], *Wk = A[2], *bk = A[3], *Wv = A[4], *bv = A[5];
  const float *Wqa = A[6], *bqa = A[7], *Wka = A[8], *bka = A[9], *Wva = A[10], *bva = A[11];
  const float *Wp = A[12], *bp = A[13], *Wpa = A[14], *bpa = A[15];
  const float *video = A[16], *action = A[17];
  float* out = (float*)d_out;

  const size_t qkv_elems = (size_t)BSZ * NHEAD * NTOK * HDIM;  // 4,227,072
  unsigned short* Wb  = (unsigned short*)d_ws;                  // 8 x 1M bf16
  unsigned short* Xb  = Wb + (size_t)8 * WSZ;                   // 4128 x 1024
  unsigned short* Qw  = Xb + (size_t)MROWS * HID;
  unsigned short* Kw  = Qw + qkv_elems;
  unsigned short* Vtw = Kw + qkv_elems;                         // (B,H,D,NTOK)
  unsigned short* ctx = Vtw + qkv_elems;                        // 4128 x 1024 bf16

  dim3 g0(512, 13);
  cvt_kernel<<<g0, 256, 0, stream>>>(Wq, Wk, Wv, Wqa, Wka, Wva, Wp, Wpa,
                                     video, action, Wb, Xb);
  dim3 g1(8, 33, 3);
  qkv128_kernel<<<g1, 256, 0, stream>>>(Xb, Wb, bq, bk, bv, bqa, bka, bva,
                                        Qw, Kw, Vtw);
  dim3 g2(33, BSZ * NHEAD);
  attn_kernel<<<g2, 256, 0, stream>>>(Qw, Kw, Vtw, ctx);
  dim3 g3(8, 33);
  proj128_kernel<<<g3, 256, 0, stream>>>(ctx, Wb, bp, bpa, out);
}